// Round 1
// baseline (251.036 us; speedup 1.0000x reference)
//
#include <hip/hip_runtime.h>
#include <hip/hip_bf16.h>
#include <math.h>
#include <stdint.h>

#define B_ROWS 2048
#define D_DIM  512
#define V_COLS 32000
#define BM 128
#define BN 128
#define BK 32
#define KSTEPS (D_DIM / BK)             // 16
#define NPART  ((V_COLS / BN) * 2)      // 500 partials per row (2 waves per block cover cols)
#define S_SC   30.0f
#define COS_M  0.8775825618903728f      // cos(0.5)
#define SIN_M  0.479425538604203f       // sin(0.5)

typedef __bf16 bf16x8 __attribute__((ext_vector_type(8)));
typedef float  f32x4  __attribute__((ext_vector_type(4)));

// ---------- helpers ----------
__device__ __forceinline__ unsigned short f2bf(float f) {
  union { float f; unsigned u; } v; v.f = f;
  unsigned r = v.u + 0x7fffu + ((v.u >> 16) & 1u);   // round-nearest-even
  return (unsigned short)(r >> 16);
}

// async global->LDS, 16B per lane. lds ptr must be wave-uniform base;
// HW scatters lane i's 16B to base + i*16.
__device__ __forceinline__ void load16_to_lds(const void* g, void* l) {
  __builtin_amdgcn_global_load_lds(
      (__attribute__((address_space(1))) void*)(g),
      (__attribute__((address_space(3))) void*)(l),
      16, 0, 0);
}

// ---------- kernel 1: row L2-normalize fp32 -> bf16 (D=512, 1 wave/row) ----------
__global__ void norm_rows_kernel(const float* __restrict__ src,
                                 unsigned short* __restrict__ dst) {
  const int lane = threadIdx.x & 63;
  const int wave = threadIdx.x >> 6;
  const int row  = blockIdx.x * 4 + wave;
  const float4* r4 = (const float4*)(src + (size_t)row * D_DIM);
  float4 v0 = r4[lane];
  float4 v1 = r4[64 + lane];
  float ss = v0.x*v0.x + v0.y*v0.y + v0.z*v0.z + v0.w*v0.w
           + v1.x*v1.x + v1.y*v1.y + v1.z*v1.z + v1.w*v1.w;
  #pragma unroll
  for (int off = 32; off >= 1; off >>= 1) ss += __shfl_xor(ss, off, 64);
  float inv = 1.0f / fmaxf(sqrtf(ss), 1e-12f);
  ushort4 o0, o1;
  o0.x = f2bf(v0.x*inv); o0.y = f2bf(v0.y*inv); o0.z = f2bf(v0.z*inv); o0.w = f2bf(v0.w*inv);
  o1.x = f2bf(v1.x*inv); o1.y = f2bf(v1.y*inv); o1.z = f2bf(v1.z*inv); o1.w = f2bf(v1.w*inv);
  ushort4* d4 = (ushort4*)(dst + (size_t)row * D_DIM);
  d4[lane]      = o0;
  d4[64 + lane] = o1;
}

// ---------- kernel 2: zero scalar output (harness poisons d_out) ----------
__global__ void zero_out_kernel(float* out) { if (threadIdx.x == 0) out[0] = 0.f; }

// ---------- kernel 3: bf16 GEMM (nx @ nW^T) fused with label-phi + per-slice softmax partials ----------
__global__ void arc_gemm_kernel(const unsigned short* __restrict__ nx,
                                const unsigned short* __restrict__ nw,
                                const int* __restrict__ labels,
                                float* __restrict__ pmax,
                                float* __restrict__ psum,
                                float* __restrict__ lbl_logit) {
  __shared__ unsigned short sA[BM * BK];   // 8 KB, row-major [row][k], unpadded (global_load_lds)
  __shared__ unsigned short sB[BN * BK];   // 8 KB

  const int tid  = threadIdx.x;            // 0..255
  const int wave = tid >> 6;               // 0..3
  const int lane = tid & 63;
  const int wm   = wave >> 1;              // wave row (0..1) -> 64 rows
  const int wn   = wave & 1;               // wave col (0..1) -> 64 cols
  const int quad = lane >> 4;              // 0..3
  const int l16  = lane & 15;
  const int m0   = blockIdx.y * BM;
  const int n0   = blockIdx.x * BN;

  f32x4 acc[4][4];
  #pragma unroll
  for (int i = 0; i < 4; ++i)
    #pragma unroll
    for (int j = 0; j < 4; ++j) acc[i][j] = (f32x4){0.f, 0.f, 0.f, 0.f};

  for (int ks = 0; ks < KSTEPS; ++ks) {
    __syncthreads();   // previous compute done before overwriting LDS
    #pragma unroll
    for (int i = 0; i < 2; ++i) {
      const int chunk = i * 256 + tid;         // 16B chunk index, 512 chunks = 128 rows * 64B
      const int row   = chunk >> 2;
      const int ko    = (chunk & 3) << 3;      // element offset within row
      const unsigned short* ga = nx + (size_t)(m0 + row) * D_DIM + ks * BK + ko;
      const unsigned short* gb = nw + (size_t)(n0 + row) * D_DIM + ks * BK + ko;
      // wave-uniform LDS base for this issue (chunks i*256 + wave*64 .. +63)
      load16_to_lds(ga, &sA[(i * 256 + wave * 64) * 8]);
      load16_to_lds(gb, &sB[(i * 256 + wave * 64) * 8]);
    }
    __syncthreads();   // drains vmcnt: tiles resident

    bf16x8 af[4], bfr[4];
    #pragma unroll
    for (int mi = 0; mi < 4; ++mi)
      af[mi] = *(const bf16x8*)&sA[(wm * 64 + mi * 16 + l16) * BK + quad * 8];
    #pragma unroll
    for (int ni = 0; ni < 4; ++ni)
      bfr[ni] = *(const bf16x8*)&sB[(wn * 64 + ni * 16 + l16) * BK + quad * 8];
    #pragma unroll
    for (int mi = 0; mi < 4; ++mi)
      #pragma unroll
      for (int ni = 0; ni < 4; ++ni)
        acc[mi][ni] = __builtin_amdgcn_mfma_f32_16x16x32_bf16(af[mi], bfr[ni], acc[mi][ni], 0, 0, 0);
  }

  // Epilogue: C/D layout col = lane&15, row = quad*4 + reg.
  // Per (mi, reg): one output row; this lane holds 4 cols (ni tiles).
  const int pidx = blockIdx.x * 2 + wn;
  #pragma unroll
  for (int mi = 0; mi < 4; ++mi) {
    #pragma unroll
    for (int r = 0; r < 4; ++r) {
      const int grow = m0 + wm * 64 + mi * 16 + quad * 4 + r;
      const int lbl  = labels[grow];
      float vals[4];
      #pragma unroll
      for (int ni = 0; ni < 4; ++ni) {
        float c = acc[mi][ni][r];
        const int gcol = n0 + wn * 64 + ni * 16 + l16;
        if (gcol == lbl) {
          float sy  = sqrtf(fminf(1.f, fmaxf(0.f, 1.f - c * c)));
          float phi = c * COS_M - sy * SIN_M;
          lbl_logit[grow] = S_SC * phi;   // exactly one lane grid-wide hits this
          c = phi;
        }
        vals[ni] = S_SC * c;
      }
      float vmax = fmaxf(fmaxf(vals[0], vals[1]), fmaxf(vals[2], vals[3]));
      float vsum = __expf(vals[0] - vmax) + __expf(vals[1] - vmax)
                 + __expf(vals[2] - vmax) + __expf(vals[3] - vmax);
      // merge across the 16 lanes sharing this row (same quad)
      #pragma unroll
      for (int off = 1; off < 16; off <<= 1) {
        float om = __shfl_xor(vmax, off, 64);
        float os = __shfl_xor(vsum, off, 64);
        float nm = fmaxf(vmax, om);
        vsum = vsum * __expf(vmax - nm) + os * __expf(om - nm);
        vmax = nm;
      }
      if (l16 == 0) {
        pmax[(size_t)grow * NPART + pidx] = vmax;
        psum[(size_t)grow * NPART + pidx] = vsum;
      }
    }
  }
}

// ---------- kernel 4: merge partials -> loss ----------
__global__ void arc_reduce_kernel(const float* __restrict__ pmax,
                                  const float* __restrict__ psum,
                                  const float* __restrict__ lbl_logit,
                                  float* __restrict__ out) {
  const int row  = blockIdx.x;
  const int lane = threadIdx.x;   // 64 threads
  const float* pm = pmax + (size_t)row * NPART;
  const float* ps = psum + (size_t)row * NPART;
  float m = -1e30f, s = 0.f;
  for (int p = lane; p < NPART; p += 64) {
    float om = pm[p], os = ps[p];
    float nm = fmaxf(m, om);
    s = s * __expf(m - nm) + os * __expf(om - nm);
    m = nm;
  }
  #pragma unroll
  for (int off = 32; off >= 1; off >>= 1) {
    float om = __shfl_xor(m, off, 64);
    float os = __shfl_xor(s, off, 64);
    float nm = fmaxf(m, om);
    s = s * __expf(m - nm) + os * __expf(om - nm);
    m = nm;
  }
  if (lane == 0) {
    float lse = m + logf(s);
    atomicAdd(out, (lse - lbl_logit[row]) * (1.0f / (float)B_ROWS));
  }
}

// ---------- launch ----------
extern "C" void kernel_launch(void* const* d_in, const int* in_sizes, int n_in,
                              void* d_out, int out_size, void* d_ws, size_t ws_size,
                              hipStream_t stream) {
  const float* x      = (const float*)d_in[0];
  const float* W      = (const float*)d_in[1];
  const int*   labels = (const int*)d_in[2];
  float* out = (float*)d_out;

  char* ws = (char*)d_ws;
  unsigned short* nx = (unsigned short*)ws;                                   // 2 MB
  unsigned short* nw = (unsigned short*)(ws + (size_t)B_ROWS * D_DIM * 2);    // 32.75 MB
  char* p = ws + (size_t)B_ROWS * D_DIM * 2 + (size_t)V_COLS * D_DIM * 2;
  float* pmax = (float*)p;  p += (size_t)B_ROWS * NPART * 4;                  // 4.1 MB
  float* psum = (float*)p;  p += (size_t)B_ROWS * NPART * 4;                  // 4.1 MB
  float* lbl_logit = (float*)p;                                               // 8 KB

  hipLaunchKernelGGL(norm_rows_kernel, dim3(B_ROWS / 4), dim3(256), 0, stream, x, nx);
  hipLaunchKernelGGL(norm_rows_kernel, dim3(V_COLS / 4), dim3(256), 0, stream, W, nw);
  hipLaunchKernelGGL(zero_out_kernel, dim3(1), dim3(64), 0, stream, out);
  hipLaunchKernelGGL(arc_gemm_kernel, dim3(V_COLS / BN, B_ROWS / BM), dim3(256), 0, stream,
                     nx, nw, labels, pmax, psum, lbl_logit);
  hipLaunchKernelGGL(arc_reduce_kernel, dim3(B_ROWS), dim3(64), 0, stream,
                     pmax, psum, lbl_logit, out);
}